// Round 4
// baseline (553.689 us; speedup 1.0000x reference)
//
#include <hip/hip_runtime.h>
#include <hip/hip_bf16.h>
#include <stdint.h>

typedef unsigned short u16;
typedef _Float16 f16;
typedef __attribute__((ext_vector_type(8))) f16 f16x8;
typedef __attribute__((ext_vector_type(4))) float f32x4;
typedef __attribute__((ext_vector_type(8))) u16 u16x8;

__device__ __forceinline__ u16 f2h(float f) {
    return __builtin_bit_cast(u16, (f16)f);
}

#define GLDS16(g, l) __builtin_amdgcn_global_load_lds( \
    (const __attribute__((address_space(1))) void*)(uintptr_t)(g), \
    (__attribute__((address_space(3))) void*)(uintptr_t)(l), 16, 0, 0)

#define WAITL() do { asm volatile("s_waitcnt lgkmcnt(0)" ::: "memory"); \
                     __builtin_amdgcn_sched_barrier(0); } while (0)
#define BARR()  do { __builtin_amdgcn_sched_barrier(0); \
                     __builtin_amdgcn_s_barrier(); \
                     __builtin_amdgcn_sched_barrier(0); } while (0)

// ---------------- weight prep ----------------
__global__ __launch_bounds__(256) void transpose_w(
    const float* __restrict__ in, u16* __restrict__ out,
    int K, int N, int rowOff)
{
    __shared__ float tile[32][33];
    int n0 = blockIdx.x * 32;
    int k0 = blockIdx.y * 32;
    int tx = threadIdx.x & 31;
    int ty = threadIdx.x >> 5;
#pragma unroll
    for (int i = 0; i < 4; ++i) {
        int k = ty + i * 8;
        tile[k][tx] = in[(size_t)(k0 + k) * N + n0 + tx];
    }
    __syncthreads();
#pragma unroll
    for (int i = 0; i < 4; ++i) {
        int n = ty + i * 8;
        out[(size_t)(rowOff + n0 + n) * K + k0 + tx] = f2h(tile[tx][n]);
    }
}

__global__ __launch_bounds__(256) void transpose_w4(
    const float* __restrict__ wq, const float* __restrict__ wk,
    const float* __restrict__ wv, const float* __restrict__ wo,
    u16* __restrict__ wqkvT, u16* __restrict__ woT)
{
    __shared__ float tile[32][33];
    const float* src[4] = {wq, wk, wv, wo};
    const int z = blockIdx.z;
    const float* in = src[z];
    u16* out = (z == 3) ? woT : (wqkvT + (size_t)z * 512 * 512);
    int n0 = blockIdx.x * 32;
    int k0 = blockIdx.y * 32;
    int tx = threadIdx.x & 31;
    int ty = threadIdx.x >> 5;
#pragma unroll
    for (int i = 0; i < 4; ++i) {
        int k = ty + i * 8;
        tile[k][tx] = in[(size_t)(k0 + k) * 512 + n0 + tx];
    }
    __syncthreads();
#pragma unroll
    for (int i = 0; i < 4; ++i) {
        int n = ty + i * 8;
        out[(size_t)(n0 + n) * 512 + k0 + tx] = f2h(tile[tx][n]);
    }
}

__global__ void pack_bias3(const float* __restrict__ bq, const float* __restrict__ bk,
                           const float* __restrict__ bv, float* __restrict__ bqkv)
{
    int i = blockIdx.x * 256 + threadIdx.x;
    float v;
    if (i < 512) v = bq[i];
    else if (i < 1024) v = bk[i - 512];
    else v = bv[i - 1024];
    bqkv[i] = v;
}

__global__ __launch_bounds__(256) void convert_x(const float* __restrict__ in,
                                                 u16* __restrict__ out)
{
    size_t i = ((size_t)blockIdx.x * 256 + threadIdx.x) * 8;
    float4 a = *(const float4*)(in + i);
    float4 b = *(const float4*)(in + i + 4);
    u16x8 r;
    r[0] = f2h(a.x); r[1] = f2h(a.y); r[2] = f2h(a.z); r[3] = f2h(a.w);
    r[4] = f2h(b.x); r[5] = f2h(b.y); r[6] = f2h(b.z); r[7] = f2h(b.w);
    *(u16x8*)(out + i) = r;
}

// ---------------- MFMA quadrant helper (all-static indexing) ----------------
template<int MG, int NG>
__device__ __forceinline__ void mmaQ(f32x4 (&acc)[8][4], const f16x8 (&a)[4][2],
                                     const f16x8 (&bb)[2][2])
{
    __builtin_amdgcn_s_setprio(1);
#pragma unroll
    for (int ks = 0; ks < 2; ++ks)
#pragma unroll
        for (int mf = 0; mf < 4; ++mf)
#pragma unroll
            for (int nf = 0; nf < 2; ++nf)
                acc[MG * 4 + mf][NG * 2 + nf] = __builtin_amdgcn_mfma_f32_16x16x32_f16(
                    a[mf][ks], bb[nf][ks], acc[MG * 4 + mf][NG * 2 + nf], 0, 0, 0);
    __builtin_amdgcn_s_setprio(0);
}

// ---------------- 256x256 8-phase GEMM: C = A[M][lda] * BT[N][ldb]^T --------
// 8 waves (2Mx4N), BK=64, double-buffered 128KB LDS, counted vmcnt(4),
// raw s_barrier phases, T2 swizzle via pre-swizzled global source,
// bijective XCD chunking on a 1-D n-fastest grid.
template<int RES, bool RELU, bool WH, bool WF32>
__global__ __launch_bounds__(512, 2) void gemm256(
    const u16* __restrict__ A, int lda,
    const u16* __restrict__ BT, int ldb,
    const float* __restrict__ bias, const float* __restrict__ res,
    u16* __restrict__ outh, float* __restrict__ outf,
    int nb_n, int N, int K)
{
    __shared__ u16 lds[65536];           // 131072 B: 2 bufs x (A 32KB | B 32KB)
    char* ldsc = (char*)lds;
    const int tid  = threadIdx.x;
    const int lane = tid & 63;
    const int w    = tid >> 6;
    const int wm   = w >> 2;             // 0..1
    const int wn   = w & 3;              // 0..3
    const int lhi  = lane >> 4;
    const int llo  = lane & 15;
    const int nwg  = gridDim.x;
    const int cpx  = nwg >> 3;
    const int logical = (blockIdx.x & 7) * cpx + (blockIdx.x >> 3);
    const int m0   = (logical / nb_n) * 256;
    const int n0   = (logical % nb_n) * 256;
    const int nt   = K >> 6;

    const int sx    = (llo & 7) << 4;    // row&7 == llo&7 for all frag rows
    const int koff0 = (lhi * 16) ^ sx;
    const int koff1 = (64 + lhi * 16) ^ sx;
    const int arow  = (wm * 128 + llo) * 128;
    const int brow  = (wn * 64 + llo) * 128;

    f32x4 acc[8][4] = {};
    f16x8 aF[4][2], bF0[2][2], bF1[2][2];

    auto stgA = [&](int b, int h, int kt) {
#pragma unroll
        for (int j = 0; j < 2; ++j) {
            int c = j * 512 + w * 64 + lane;
            int r = c >> 3;
            int ch = (c & 7) ^ (r & 7);
            const u16* g = A + (size_t)(m0 + h * 128 + r) * lda + kt + ch * 8;
            char* l = ldsc + b * 65536 + h * 16384 + ((j * 512 + w * 64) << 4);
            GLDS16(g, l);
        }
    };
    auto stgB = [&](int b, int h, int kt) {
#pragma unroll
        for (int j = 0; j < 2; ++j) {
            int c = j * 512 + w * 64 + lane;
            int r = c >> 3;
            int ch = (c & 7) ^ (r & 7);
            const u16* g = BT + (size_t)(n0 + h * 128 + r) * ldb + kt + ch * 8;
            char* l = ldsc + b * 65536 + 32768 + h * 16384 + ((j * 512 + w * 64) << 4);
            GLDS16(g, l);
        }
    };
    auto rdA = [&](int b, int mf, int ks) -> f16x8 {
        return *(const f16x8*)(ldsc + b * 65536 + arow + mf * 2048
                               + (ks ? koff1 : koff0));
    };
    auto rdB = [&](int b, int nf, int ks) -> f16x8 {
        return *(const f16x8*)(ldsc + b * 65536 + 32768 + brow + nf * 2048
                               + (ks ? koff1 : koff0));
    };

    // ---- prologue: tile0 complete (8 loads), tile1 B-halves (4 loads) ----
    stgA(0, 0, 0); stgA(0, 1, 0);
    stgB(0, 0, 0); stgB(0, 1, 0);
    stgB(1, 0, 64); stgB(1, 1, 64);
    asm volatile("s_waitcnt vmcnt(4)" ::: "memory");
    BARR();

    // ---- main loop: one K-tile per iteration, 4 phases ----
    for (int t = 0; t < nt; ++t) {
        const int b = t & 1;
        int t1 = t + 1; if (t1 >= nt) t1 -= nt;   // wrapped (redundant) stages
        int t2 = t + 2; if (t2 >= nt) t2 -= nt;   // on the final tiles

        // P1: read A m0-3 + B n0-1; stage A-half0(t+1) -> buf b^1
#pragma unroll
        for (int mf = 0; mf < 4; ++mf) {
            aF[mf][0] = rdA(b, mf, 0); aF[mf][1] = rdA(b, mf, 1);
        }
#pragma unroll
        for (int nf = 0; nf < 2; ++nf) {
            bF0[nf][0] = rdB(b, nf, 0); bF0[nf][1] = rdB(b, nf, 1);
        }
        stgA(b ^ 1, 0, t1 << 6);
        __builtin_amdgcn_s_barrier();
        WAITL();
        mmaQ<0, 0>(acc, aF, bF0);
        BARR();

        // P2: read B n2-3; stage A-half1(t+1) -> buf b^1
#pragma unroll
        for (int nf = 0; nf < 2; ++nf) {
            bF1[nf][0] = rdB(b, nf + 2, 0); bF1[nf][1] = rdB(b, nf + 2, 1);
        }
        stgA(b ^ 1, 1, t1 << 6);
        __builtin_amdgcn_s_barrier();
        WAITL();
        mmaQ<0, 1>(acc, aF, bF1);
        BARR();

        // P3: read A m4-7; stage B-half0(t+2) -> buf b
#pragma unroll
        for (int mf = 0; mf < 4; ++mf) {
            aF[mf][0] = rdA(b, mf + 4, 0); aF[mf][1] = rdA(b, mf + 4, 1);
        }
        stgB(b, 0, t2 << 6);
        __builtin_amdgcn_s_barrier();
        WAITL();
        mmaQ<1, 0>(acc, aF, bF0);
        BARR();

        // P4: no reads; stage B-half1(t+2) -> buf b; counted vmcnt
        stgB(b, 1, t2 << 6);
        __builtin_amdgcn_s_barrier();
        __builtin_amdgcn_sched_barrier(0);
        mmaQ<1, 1>(acc, aF, bF1);
        asm volatile("s_waitcnt vmcnt(4)" ::: "memory");
        BARR();
    }

    // ---- epilogue ----
#pragma unroll
    for (int mf = 0; mf < 8; ++mf) {
#pragma unroll
        for (int nf = 0; nf < 4; ++nf) {
            const int col = n0 + wn * 64 + nf * 16 + llo;
            const float bia = bias[col];
#pragma unroll
            for (int r = 0; r < 4; ++r) {
                const int row = m0 + wm * 128 + mf * 16 + lhi * 4 + r;
                float v = acc[mf][nf][r] + bia;
                if constexpr (RES) v += res[(size_t)row * N + col];
                if constexpr (RELU) v = fmaxf(v, 0.f);
                if constexpr (WF32) outf[(size_t)row * N + col] = v;
                if constexpr (WH)   outh[(size_t)row * N + col] = f2h(v);
            }
        }
    }
}

// ---------------- fused attention, one block per (batch, head) --------------
__global__ __launch_bounds__(256, 2) void attn_kernel(
    const u16* __restrict__ qkv, u16* __restrict__ attn)
{
    __shared__ u16 VT[128 * 128];
    __shared__ u16 Plds[4 * 32 * 128];
    const int tid  = threadIdx.x;
    const int lane = tid & 63;
    const int wv   = tid >> 6;
    const int b    = blockIdx.x >> 2;
    const int hh   = blockIdx.x & 3;
    const int lhi  = lane >> 4;
    const int llo  = lane & 15;
    const u16* base = qkv + (size_t)b * 128 * 1536;

#pragma unroll
    for (int i = 0; i < 8; ++i) {
        int c = i * 256 + tid;
        int t = c >> 4;
        int ch = c & 15;
        uint4 raw = *(const uint4*)(base + (size_t)t * 1536 + 1024 + hh * 128 + ch * 8);
        const u16* e = (const u16*)&raw;
#pragma unroll
        for (int j = 0; j < 8; ++j) {
            int d = ch * 8 + j;
            *(u16*)((char*)VT + ((d << 8) + ((t * 2) ^ ((d & 7) << 4)))) = e[j];
        }
    }

    f16x8 qf[2][4];
#pragma unroll
    for (int fm = 0; fm < 2; ++fm)
#pragma unroll
        for (int fk = 0; fk < 4; ++fk) {
            int srow = wv * 32 + fm * 16 + llo;
            qf[fm][fk] = *(const f16x8*)(base + (size_t)srow * 1536 + hh * 128 + fk * 32 + lhi * 8);
        }

    f32x4 acc[2][8] = {};
#pragma unroll
    for (int ft = 0; ft < 8; ++ft) {
        f16x8 kf[4];
#pragma unroll
        for (int fk = 0; fk < 4; ++fk) {
            int trow = ft * 16 + llo;
            kf[fk] = *(const f16x8*)(base + (size_t)trow * 1536 + 512 + hh * 128 + fk * 32 + lhi * 8);
        }
#pragma unroll
        for (int fm = 0; fm < 2; ++fm)
#pragma unroll
            for (int fk = 0; fk < 4; ++fk)
                acc[fm][ft] = __builtin_amdgcn_mfma_f32_16x16x32_f16(
                    qf[fm][fk], kf[fk], acc[fm][ft], 0, 0, 0);
    }

    float inv[2][4];
#pragma unroll
    for (int fm = 0; fm < 2; ++fm)
#pragma unroll
        for (int r = 0; r < 4; ++r) {
            float mx = acc[fm][0][r];
#pragma unroll
            for (int ft = 1; ft < 8; ++ft) mx = fmaxf(mx, acc[fm][ft][r]);
            mx = fmaxf(mx, __shfl_xor(mx, 1, 64));
            mx = fmaxf(mx, __shfl_xor(mx, 2, 64));
            mx = fmaxf(mx, __shfl_xor(mx, 4, 64));
            mx = fmaxf(mx, __shfl_xor(mx, 8, 64));
            float s = 0.f;
#pragma unroll
            for (int ft = 0; ft < 8; ++ft) {
                float p = __expf(acc[fm][ft][r] - mx);
                acc[fm][ft][r] = p;
                s += p;
            }
            s += __shfl_xor(s, 1, 64);
            s += __shfl_xor(s, 2, 64);
            s += __shfl_xor(s, 4, 64);
            s += __shfl_xor(s, 8, 64);
            inv[fm][r] = 1.f / s;
        }

    char* Pw = (char*)Plds + wv * 8192;
#pragma unroll
    for (int fm = 0; fm < 2; ++fm)
#pragma unroll
        for (int ft = 0; ft < 8; ++ft)
#pragma unroll
            for (int r = 0; r < 4; ++r) {
                int m = fm * 16 + lhi * 4 + r;
                int t = ft * 16 + llo;
                *(u16*)(Pw + ((m << 8) + ((t * 2) ^ ((m & 7) << 4)))) = f2h(acc[fm][ft][r]);
            }

    __syncthreads();

    f16x8 pf[2][4];
#pragma unroll
    for (int fm = 0; fm < 2; ++fm)
#pragma unroll
        for (int k2 = 0; k2 < 4; ++k2) {
            int m = fm * 16 + llo;
            pf[fm][k2] = *(const f16x8*)(Pw +
                ((m << 8) + ((k2 * 64 + (lhi << 4)) ^ ((m & 7) << 4))));
        }

    f32x4 o[2][8] = {};
#pragma unroll
    for (int fd = 0; fd < 8; ++fd) {
        f16x8 vf[4];
#pragma unroll
        for (int k2 = 0; k2 < 4; ++k2) {
            int d = fd * 16 + llo;
            vf[k2] = *(const f16x8*)((const char*)VT +
                ((d << 8) + ((k2 * 64 + (lhi << 4)) ^ ((d & 7) << 4))));
        }
#pragma unroll
        for (int fm = 0; fm < 2; ++fm)
#pragma unroll
            for (int k2 = 0; k2 < 4; ++k2)
                o[fm][fd] = __builtin_amdgcn_mfma_f32_16x16x32_f16(
                    pf[fm][k2], vf[k2], o[fm][fd], 0, 0, 0);
    }

#pragma unroll
    for (int fm = 0; fm < 2; ++fm)
#pragma unroll
        for (int fd = 0; fd < 8; ++fd)
#pragma unroll
            for (int r = 0; r < 4; ++r) {
                int row = b * 128 + wv * 32 + fm * 16 + lhi * 4 + r;
                int col = hh * 128 + fd * 16 + llo;
                attn[(size_t)row * 512 + col] = f2h(o[fm][fd][r] * inv[fm][r]);
            }
}

// ---------------- launch -----------------------------------------------------
extern "C" void kernel_launch(void* const* d_in, const int* in_sizes, int n_in,
                              void* d_out, int out_size, void* d_ws, size_t ws_size,
                              hipStream_t stream)
{
    const float* x  = (const float*)d_in[0];
    const float* wq = (const float*)d_in[1];
    const float* bq = (const float*)d_in[2];
    const float* wk = (const float*)d_in[3];
    const float* bk = (const float*)d_in[4];
    const float* wv = (const float*)d_in[5];
    const float* bv = (const float*)d_in[6];
    const float* wo = (const float*)d_in[7];
    const float* bo = (const float*)d_in[8];
    const float* w1 = (const float*)d_in[9];
    const float* b1 = (const float*)d_in[10];
    const float* w2 = (const float*)d_in[11];
    const float* b2 = (const float*)d_in[12];
    float* out = (float*)d_out;

    char* ws = (char*)d_ws;
    u16*   wqkvT = (u16*)(ws + 0);                 // [1536][512] f16  1,572,864
    u16*   woT   = (u16*)(ws + 1572864);           // [512][512]         524,288
    u16*   w1T   = (u16*)(ws + 2097152);           // [2048][512]      2,097,152
    u16*   w2T   = (u16*)(ws + 4194304);           // [512][2048]      2,097,152
    float* bqkv  = (float*)(ws + 6291456);         // [1536]               6,144
    u16*   xf    = (u16*)(ws + 6297600);           // [M][512]  50,331,648  (also attno)
    u16*   qkv   = (u16*)(ws + 56629248);          // [M][1536] 150,994,944
    u16*   attno = xf;                             // attn out (xf dead)
    u16*   x1h   = qkv;                            // [M][512] f16 (qkv dead after attn)
    u16*   hbuf  = (u16*)(ws + 106960896);         // [M][2048] 201,326,592 -> 308,287,488
    float* x1f   = (float*)d_out;                  // [M][512] fp32 residual, out in-place

    // ---- prep ----
    transpose_w4<<<dim3(16, 16, 4), 256, 0, stream>>>(wq, wk, wv, wo, wqkvT, woT);
    transpose_w<<<dim3(64, 16), 256, 0, stream>>>(w1, w1T, 512, 2048, 0);
    transpose_w<<<dim3(16, 64), 256, 0, stream>>>(w2, w2T, 2048, 512, 0);
    pack_bias3<<<6, 256, 0, stream>>>(bq, bk, bv, bqkv);
    convert_x<<<12288, 256, 0, stream>>>(x, xf);

    // ---- qkv = x @ [wq|wk|wv] + b ----
    gemm256<0, false, true, false><<<1152, 512, 0, stream>>>(
        xf, 512, wqkvT, 512, bqkv, nullptr, qkv, nullptr, 6, 1536, 512);
    // ---- attention -> attno ----
    attn_kernel<<<1536, 256, 0, stream>>>(qkv, attno);
    // ---- x1 = x + attn @ wo + bo  (f16 -> x1h, fp32 -> d_out) ----
    gemm256<1, false, true, true><<<384, 512, 0, stream>>>(
        attno, 512, woT, 512, bo, x, x1h, x1f, 2, 512, 512);
    // ---- h = relu(x1 @ w1 + b1) ----
    gemm256<0, true, true, false><<<1536, 512, 0, stream>>>(
        x1h, 512, w1T, 512, b1, nullptr, hbuf, nullptr, 8, 2048, 512);
    // ---- out = x1 + h @ w2 + b2 (in-place on d_out) ----
    gemm256<1, false, false, true><<<384, 512, 0, stream>>>(
        hbuf, 2048, w2T, 2048, b2, x1f, nullptr, out, 2, 512, 2048);
}

// Round 5
// 442.492 us; speedup vs baseline: 1.2513x; 1.2513x over previous
//
#include <hip/hip_runtime.h>
#include <hip/hip_bf16.h>
#include <stdint.h>

typedef unsigned short u16;
typedef _Float16 f16;
typedef __attribute__((ext_vector_type(8))) f16 f16x8;
typedef __attribute__((ext_vector_type(4))) float f32x4;
typedef __attribute__((ext_vector_type(8))) u16 u16x8;

__device__ __forceinline__ u16 f2h(float f) {
    return __builtin_bit_cast(u16, (f16)f);
}
__device__ __forceinline__ float h2f(u16 u) {
    return (float)__builtin_bit_cast(f16, u);
}

#define GLDS16(g, l) __builtin_amdgcn_global_load_lds( \
    (const __attribute__((address_space(1))) void*)(uintptr_t)(g), \
    (__attribute__((address_space(3))) void*)(uintptr_t)(l), 16, 0, 0)

// ---------------- weight prep ----------------
// in: [K][N] fp32 row-major -> out[(rowOff+n)][K] f16 (B^T layout), ld = K
__global__ __launch_bounds__(256) void transpose_w(
    const float* __restrict__ in, u16* __restrict__ out,
    int K, int N, int rowOff)
{
    __shared__ float tile[32][33];
    int n0 = blockIdx.x * 32;
    int k0 = blockIdx.y * 32;
    int tx = threadIdx.x & 31;
    int ty = threadIdx.x >> 5;
#pragma unroll
    for (int i = 0; i < 4; ++i) {
        int k = ty + i * 8;
        tile[k][tx] = in[(size_t)(k0 + k) * N + n0 + tx];
    }
    __syncthreads();
#pragma unroll
    for (int i = 0; i < 4; ++i) {
        int n = ty + i * 8;
        out[(size_t)(rowOff + n0 + n) * K + k0 + tx] = f2h(tile[tx][n]);
    }
}

// four 512x512 transposes in one dispatch (z selects source/dest)
__global__ __launch_bounds__(256) void transpose_w4(
    const float* __restrict__ wq, const float* __restrict__ wk,
    const float* __restrict__ wv, const float* __restrict__ wo,
    u16* __restrict__ wqkvT, u16* __restrict__ woT)
{
    __shared__ float tile[32][33];
    const float* src[4] = {wq, wk, wv, wo};
    const int z = blockIdx.z;
    const float* in = src[z];
    u16* out = (z == 3) ? woT : (wqkvT + (size_t)z * 512 * 512);
    int n0 = blockIdx.x * 32;
    int k0 = blockIdx.y * 32;
    int tx = threadIdx.x & 31;
    int ty = threadIdx.x >> 5;
#pragma unroll
    for (int i = 0; i < 4; ++i) {
        int k = ty + i * 8;
        tile[k][tx] = in[(size_t)(k0 + k) * 512 + n0 + tx];
    }
    __syncthreads();
#pragma unroll
    for (int i = 0; i < 4; ++i) {
        int n = ty + i * 8;
        out[(size_t)(n0 + n) * 512 + k0 + tx] = f2h(tile[tx][n]);
    }
}

__global__ void pack_bias3(const float* __restrict__ bq, const float* __restrict__ bk,
                           const float* __restrict__ bv, float* __restrict__ bqkv)
{
    int i = blockIdx.x * 256 + threadIdx.x;
    float v;
    if (i < 512) v = bq[i];
    else if (i < 1024) v = bk[i - 512];
    else v = bv[i - 1024];
    bqkv[i] = v;
}

// x [M*512] fp32 -> f16
__global__ __launch_bounds__(256) void convert_x(const float* __restrict__ in,
                                                 u16* __restrict__ out)
{
    size_t i = ((size_t)blockIdx.x * 256 + threadIdx.x) * 8;
    float4 a = *(const float4*)(in + i);
    float4 b = *(const float4*)(in + i + 4);
    u16x8 r;
    r[0] = f2h(a.x); r[1] = f2h(a.y); r[2] = f2h(a.z); r[3] = f2h(a.w);
    r[4] = f2h(b.x); r[5] = f2h(b.y); r[6] = f2h(b.z); r[7] = f2h(b.w);
    *(u16x8*)(out + i) = r;
}

// ---------------- GEMM: C = A[M][lda] * BT[N][ldb]^T ------------------------
// 128x128 tile, BK=64, 4 waves, global_load_lds w16, T2 swizzle via
// pre-swizzled global source, 1-D grid with n-fastest order + bijective
// XCD chunking (T1).  RES: 0 none, 2 = f16 residual.
template<int RES, bool RELU, bool WH, bool WF32>
__global__ __launch_bounds__(256, 2) void gemm_bt(
    const u16* __restrict__ A, int lda,
    const u16* __restrict__ BT, int ldb,
    const float* __restrict__ bias, const void* __restrict__ res,
    u16* __restrict__ outh, float* __restrict__ outf,
    int nb_n, int N, int K)
{
    __shared__ u16 As[128 * 64];
    __shared__ u16 Bs[128 * 64];
    const int tid  = threadIdx.x;
    const int lane = tid & 63;
    const int wv   = tid >> 6;
    const int nwg  = gridDim.x;
    const int cpx  = nwg >> 3;
    const int logical = (blockIdx.x & 7) * cpx + (blockIdx.x >> 3);
    const int m0   = (logical / nb_n) * 128;
    const int n0   = (logical % nb_n) * 128;
    const int wm   = (wv >> 1) * 64;
    const int wn   = (wv & 1) * 64;
    const int lhi  = lane >> 4;
    const int llo  = lane & 15;

    f32x4 acc[4][4] = {};

    for (int kt = 0; kt < K; kt += 64) {
        __syncthreads();
#pragma unroll
        for (int i = 0; i < 4; ++i) {
            int c = i * 256 + tid;              // 16B chunk id
            int row = c >> 3;                   // tile row 0..127
            int chunk = (c & 7) ^ (row & 7);    // inverse-swizzled source
            const u16* ga = A  + (size_t)(m0 + row) * lda + kt + chunk * 8;
            const u16* gb = BT + (size_t)(n0 + row) * ldb + kt + chunk * 8;
            char* la = (char*)As + ((i * 256 + wv * 64) << 4);
            char* lb = (char*)Bs + ((i * 256 + wv * 64) << 4);
            GLDS16(ga, la);
            GLDS16(gb, lb);
        }
        __syncthreads();
#pragma unroll
        for (int fk = 0; fk < 2; ++fk) {
            f16x8 af[4], bfr[4];
#pragma unroll
            for (int f = 0; f < 4; ++f) {
                int ra = wm + f * 16 + llo;
                af[f] = *(const f16x8*)((const char*)As +
                        ((ra << 7) + ((fk * 64 + (lhi << 4)) ^ ((ra & 7) << 4))));
                int rb = wn + f * 16 + llo;
                bfr[f] = *(const f16x8*)((const char*)Bs +
                        ((rb << 7) + ((fk * 64 + (lhi << 4)) ^ ((rb & 7) << 4))));
            }
#pragma unroll
            for (int fm = 0; fm < 4; ++fm)
#pragma unroll
                for (int fn = 0; fn < 4; ++fn)
                    acc[fm][fn] = __builtin_amdgcn_mfma_f32_16x16x32_f16(
                        af[fm], bfr[fn], acc[fm][fn], 0, 0, 0);
        }
    }

    const int cr = lhi * 4;
#pragma unroll
    for (int fm = 0; fm < 4; ++fm) {
#pragma unroll
        for (int fn = 0; fn < 4; ++fn) {
            const int col = n0 + wn + fn * 16 + llo;
            const float bia = bias[col];
#pragma unroll
            for (int r = 0; r < 4; ++r) {
                const int row = m0 + wm + fm * 16 + cr + r;
                float v = acc[fm][fn][r] + bia;
                if constexpr (RES == 2) v += h2f(((const u16*)res)[(size_t)row * N + col]);
                if constexpr (RELU) v = fmaxf(v, 0.f);
                if constexpr (WF32) outf[(size_t)row * N + col] = v;
                if constexpr (WH)   outh[(size_t)row * N + col] = f2h(v);
            }
        }
    }
}

// ---------------- fused attention, one block per (batch, head) --------------
// qkv: [B*S][1536] f16 (q | k | v, each 512 wide). attn out: [B*S][512] f16.
__global__ __launch_bounds__(256, 2) void attn_kernel(
    const u16* __restrict__ qkv, u16* __restrict__ attn)
{
    __shared__ u16 VT[128 * 128];        // V^T [d][t], XOR-swizzled rows
    __shared__ u16 Plds[4 * 32 * 128];   // per-wave P [32][t], XOR-swizzled
    const int tid  = threadIdx.x;
    const int lane = tid & 63;
    const int wv   = tid >> 6;
    const int b    = blockIdx.x >> 2;
    const int hh   = blockIdx.x & 3;
    const int lhi  = lane >> 4;
    const int llo  = lane & 15;
    const u16* base = qkv + (size_t)b * 128 * 1536;

#pragma unroll
    for (int i = 0; i < 8; ++i) {
        int c = i * 256 + tid;
        int t = c >> 4;
        int ch = c & 15;
        uint4 raw = *(const uint4*)(base + (size_t)t * 1536 + 1024 + hh * 128 + ch * 8);
        const u16* e = (const u16*)&raw;
#pragma unroll
        for (int j = 0; j < 8; ++j) {
            int d = ch * 8 + j;
            *(u16*)((char*)VT + ((d << 8) + ((t * 2) ^ ((d & 7) << 4)))) = e[j];
        }
    }

    f16x8 qf[2][4];
#pragma unroll
    for (int fm = 0; fm < 2; ++fm)
#pragma unroll
        for (int fk = 0; fk < 4; ++fk) {
            int srow = wv * 32 + fm * 16 + llo;
            qf[fm][fk] = *(const f16x8*)(base + (size_t)srow * 1536 + hh * 128 + fk * 32 + lhi * 8);
        }

    f32x4 acc[2][8] = {};
#pragma unroll
    for (int ft = 0; ft < 8; ++ft) {
        f16x8 kf[4];
#pragma unroll
        for (int fk = 0; fk < 4; ++fk) {
            int trow = ft * 16 + llo;
            kf[fk] = *(const f16x8*)(base + (size_t)trow * 1536 + 512 + hh * 128 + fk * 32 + lhi * 8);
        }
#pragma unroll
        for (int fm = 0; fm < 2; ++fm)
#pragma unroll
            for (int fk = 0; fk < 4; ++fk)
                acc[fm][ft] = __builtin_amdgcn_mfma_f32_16x16x32_f16(
                    qf[fm][fk], kf[fk], acc[fm][ft], 0, 0, 0);
    }

    float inv[2][4];
#pragma unroll
    for (int fm = 0; fm < 2; ++fm)
#pragma unroll
        for (int r = 0; r < 4; ++r) {
            float mx = acc[fm][0][r];
#pragma unroll
            for (int ft = 1; ft < 8; ++ft) mx = fmaxf(mx, acc[fm][ft][r]);
            mx = fmaxf(mx, __shfl_xor(mx, 1, 64));
            mx = fmaxf(mx, __shfl_xor(mx, 2, 64));
            mx = fmaxf(mx, __shfl_xor(mx, 4, 64));
            mx = fmaxf(mx, __shfl_xor(mx, 8, 64));
            float s = 0.f;
#pragma unroll
            for (int ft = 0; ft < 8; ++ft) {
                float p = __expf(acc[fm][ft][r] - mx);
                acc[fm][ft][r] = p;
                s += p;
            }
            s += __shfl_xor(s, 1, 64);
            s += __shfl_xor(s, 2, 64);
            s += __shfl_xor(s, 4, 64);
            s += __shfl_xor(s, 8, 64);
            inv[fm][r] = 1.f / s;
        }

    char* Pw = (char*)Plds + wv * 8192;
#pragma unroll
    for (int fm = 0; fm < 2; ++fm)
#pragma unroll
        for (int ft = 0; ft < 8; ++ft)
#pragma unroll
            for (int r = 0; r < 4; ++r) {
                int m = fm * 16 + lhi * 4 + r;
                int t = ft * 16 + llo;
                *(u16*)(Pw + ((m << 8) + ((t * 2) ^ ((m & 7) << 4)))) = f2h(acc[fm][ft][r]);
            }

    __syncthreads();

    f16x8 pf[2][4];
#pragma unroll
    for (int fm = 0; fm < 2; ++fm)
#pragma unroll
        for (int k2 = 0; k2 < 4; ++k2) {
            int m = fm * 16 + llo;
            pf[fm][k2] = *(const f16x8*)(Pw +
                ((m << 8) + ((k2 * 64 + (lhi << 4)) ^ ((m & 7) << 4))));
        }

    f32x4 o[2][8] = {};
#pragma unroll
    for (int fd = 0; fd < 8; ++fd) {
        f16x8 vf[4];
#pragma unroll
        for (int k2 = 0; k2 < 4; ++k2) {
            int d = fd * 16 + llo;
            vf[k2] = *(const f16x8*)((const char*)VT +
                ((d << 8) + ((k2 * 64 + (lhi << 4)) ^ ((d & 7) << 4))));
        }
#pragma unroll
        for (int fm = 0; fm < 2; ++fm)
#pragma unroll
            for (int k2 = 0; k2 < 4; ++k2)
                o[fm][fd] = __builtin_amdgcn_mfma_f32_16x16x32_f16(
                    pf[fm][k2], vf[k2], o[fm][fd], 0, 0, 0);
    }

#pragma unroll
    for (int fm = 0; fm < 2; ++fm)
#pragma unroll
        for (int fd = 0; fd < 8; ++fd)
#pragma unroll
            for (int r = 0; r < 4; ++r) {
                int row = b * 128 + wv * 32 + fm * 16 + lhi * 4 + r;
                int col = hh * 128 + fd * 16 + llo;
                attn[(size_t)row * 512 + col] = f2h(o[fm][fd][r] * inv[fm][r]);
            }
}

// ---------------- launch -----------------------------------------------------
extern "C" void kernel_launch(void* const* d_in, const int* in_sizes, int n_in,
                              void* d_out, int out_size, void* d_ws, size_t ws_size,
                              hipStream_t stream)
{
    const float* x  = (const float*)d_in[0];
    const float* wq = (const float*)d_in[1];
    const float* bq = (const float*)d_in[2];
    const float* wk = (const float*)d_in[3];
    const float* bk = (const float*)d_in[4];
    const float* wv = (const float*)d_in[5];
    const float* bv = (const float*)d_in[6];
    const float* wo = (const float*)d_in[7];
    const float* bo = (const float*)d_in[8];
    const float* w1 = (const float*)d_in[9];
    const float* b1 = (const float*)d_in[10];
    const float* w2 = (const float*)d_in[11];
    const float* b2 = (const float*)d_in[12];
    float* out = (float*)d_out;

    char* ws = (char*)d_ws;
    u16*   wqkvT = (u16*)(ws + 0);                 // [1536][512] f16  1,572,864
    u16*   woT   = (u16*)(ws + 1572864);           // [512][512]         524,288
    u16*   w1T   = (u16*)(ws + 2097152);           // [2048][512]      2,097,152
    u16*   w2T   = (u16*)(ws + 4194304);           // [512][2048]      2,097,152
    float* bqkv  = (float*)(ws + 6291456);         // [1536]               6,144
    u16*   xf    = (u16*)(ws + 6297600);           // [M][512]  50,331,648
    u16*   qkv   = (u16*)(ws + 56629248);          // [M][1536] 150,994,944
    u16*   attno = (u16*)(ws + 207624192);         // [M][512]   50,331,648 -> 257,955,840
    u16*   x1h   = xf;                             // in-place over xf (same-elem r/w)
    u16*   hbuf  = qkv;                            // [M][2048] over dead qkv+attno

    // ---- prep ----
    transpose_w4<<<dim3(16, 16, 4), 256, 0, stream>>>(wq, wk, wv, wo, wqkvT, woT);
    transpose_w<<<dim3(64, 16), 256, 0, stream>>>(w1, w1T, 512, 2048, 0);
    transpose_w<<<dim3(16, 64), 256, 0, stream>>>(w2, w2T, 2048, 512, 0);
    pack_bias3<<<6, 256, 0, stream>>>(bq, bk, bv, bqkv);
    convert_x<<<12288, 256, 0, stream>>>(x, xf);

    // ---- qkv = x @ [wq|wk|wv] + b ----
    gemm_bt<0, false, true, false><<<4608, 256, 0, stream>>>(
        xf, 512, wqkvT, 512, bqkv, nullptr, qkv, nullptr, 12, 1536, 512);
    // ---- attention -> attno ----
    attn_kernel<<<1536, 256, 0, stream>>>(qkv, attno);
    // ---- x1 = xf + attn @ wo + bo  (f16, in-place over xf) ----
    gemm_bt<2, false, true, false><<<1536, 256, 0, stream>>>(
        attno, 512, woT, 512, bo, xf, x1h, nullptr, 4, 512, 512);
    // ---- h = relu(x1 @ w1 + b1) ----
    gemm_bt<0, true, true, false><<<6144, 256, 0, stream>>>(
        x1h, 512, w1T, 512, b1, nullptr, hbuf, nullptr, 16, 2048, 512);
    // ---- out = x1 + h @ w2 + b2 (fp32 to d_out) ----
    gemm_bt<2, false, false, true><<<1536, 256, 0, stream>>>(
        hbuf, 2048, w2T, 2048, b2, x1h, nullptr, out, 4, 512, 2048);
}